// Round 5
// baseline (67.475 us; speedup 1.0000x reference)
//
#include <hip/hip_runtime.h>

// Problem constants (from reference):
#define BB 8
#define NN 32768
#define CC 4
#define MM 11          // memory length (FIR taps)
#define KK 55          // D*M
#define THREADS 256
#define HALO (MM - 1)              // 10
#define SS (THREADS + HALO)        // 266 staged samples per block

// out[b,c,n] = sum_{j=0..10} z[n-10+j] * P_{c,j}(|z[n-10+j]|)
// P_{c,j}(a) = sum_{d=0..4} W[c, d*11+j] * a^d ; z[t]=x[b,t,c,0]+i x[b,t,c,1], 0 for t<0.
//
// Round-5 design (= round-3 structure, LDS traffic cut 33%):
//  - blockIdx.z = channel pair (weights SGPR-uniform, 32 waves/CU total).
//  - Only z staged in LDS (float4/sample, 4.3 KB/block); |z| recomputed in the
//    consumer via even/odd polynomial split so the sqrt sits OFF the Horner
//    critical path:  P = (w0 + w2 r2 + w4 r2^2) + |z|*(w1 + w3 r2),  r2=|z|^2.
//  - LDS pipe: 11 b128/thread (~1.8 us/CU) ; VALU ~1.8 us ; both < HBM 2.6 us.

__global__ __launch_bounds__(THREADS, 8)
void gmp_kernel(const float* __restrict__ x,
                const float* __restrict__ W,
                float* __restrict__ out) {
    __shared__ float4 zs[SS];    // (re0, im0, re1, im1) for this block's channel pair

    const int tid = threadIdx.x;
    const int b  = blockIdx.y;
    const int h  = blockIdx.z;               // channel pair: channels 2h, 2h+1
    const int n0 = blockIdx.x * THREADS;

    const float4* xg = (const float4*)x + (size_t)b * NN * 2;

    // Stage samples t = n0-10 .. n0+255 for this channel pair (zero-fill t<0).
    for (int s = tid; s < SS; s += THREADS) {
        const int t = n0 - HALO + s;
        float4 v = make_float4(0.f, 0.f, 0.f, 0.f);
        if (t >= 0) v = xg[2 * t + h];
        zs[s] = v;
    }
    __syncthreads();

    // Weight rows for this pair — wave-uniform -> scalar loads.
    const float* W0 = W + (2 * h) * KK;
    const float* W1 = W + (2 * h + 1) * KK;

    float ar0 = 0.f, ai0 = 0.f, ar1 = 0.f, ai1 = 0.f;

    #pragma unroll
    for (int j = 0; j < MM; j++) {
        const float4 v = zs[tid + j];
        // channel 2h
        {
            const float r2 = fmaf(v.x, v.x, v.y * v.y);
            const float a  = sqrtf(r2);                 // off critical path
            float e = fmaf(r2, W0[4 * MM + j], W0[2 * MM + j]);
            e = fmaf(r2, e, W0[0 * MM + j]);
            const float o = fmaf(r2, W0[3 * MM + j], W0[1 * MM + j]);
            const float p = fmaf(a, o, e);
            ar0 = fmaf(v.x, p, ar0);
            ai0 = fmaf(v.y, p, ai0);
        }
        // channel 2h+1
        {
            const float r2 = fmaf(v.z, v.z, v.w * v.w);
            const float a  = sqrtf(r2);
            float e = fmaf(r2, W1[4 * MM + j], W1[2 * MM + j]);
            e = fmaf(r2, e, W1[0 * MM + j]);
            const float o = fmaf(r2, W1[3 * MM + j], W1[1 * MM + j]);
            const float p = fmaf(a, o, e);
            ar1 = fmaf(v.z, p, ar1);
            ai1 = fmaf(v.w, p, ai1);
        }
    }

    // out[b,n,c,{re,im}]: channels 2h,2h+1 -> 16 contiguous bytes.
    const int n = n0 + tid;
    float4* og = (float4*)out + ((size_t)(b * NN + n) * 2 + h);
    *og = make_float4(ar0, ai0, ar1, ai1);
}

extern "C" void kernel_launch(void* const* d_in, const int* in_sizes, int n_in,
                              void* d_out, int out_size, void* d_ws, size_t ws_size,
                              hipStream_t stream) {
    const float* x = (const float*)d_in[0];   // [B,N,C,2] fp32
    const float* W = (const float*)d_in[1];   // [C,K] fp32
    float* out = (float*)d_out;               // [B,N,C,2] fp32

    dim3 grid(NN / THREADS, BB, 2);           // 128 x 8 x 2 = 2048 blocks
    gmp_kernel<<<grid, THREADS, 0, stream>>>(x, W, out);
}

// Round 6
// 62.537 us; speedup vs baseline: 1.0790x; 1.0790x over previous
//
#include <hip/hip_runtime.h>

// Problem constants (from reference):
#define BB 8
#define NN 32768
#define CC 4
#define MM 11          // memory length (FIR taps)
#define KK 55          // D*M
#define THREADS 256
#define HALO (MM - 1)              // 10
#define SS (THREADS + HALO)        // 266 staged samples per block

// out[b,c,n] = sum_{j=0..10} z[n-10+j] * ( sum_d W[c, d*11+j] * |z[n-10+j]|^d )
// z[t] = x[b,t,c,0] + i x[b,t,c,1], zero for t<0.
//
// FINAL (round-3 structure — empirical best across 5 variants):
//  - blockIdx.z selects a channel PAIR (h=0 -> ch0/1, h=1 -> ch2/3): doubles
//    total waves to 32/CU (full residency) for latency hiding; weight rows
//    stay SGPR-uniform (h is a block index) -> scalar loads, constant cache.
//  - Per-block LDS stage of 266 samples (z + precomputed |z|); amp computed
//    once per sample, reused by 11 consumers. Zero bank conflicts measured.
//  - Per-thread consume: 11 ds_read_b128 + 11 ds_read_b64, 132 fma.
//  - Pipe model per CU @32 waves: HBM 2.6 us (floor), LDS ~2.7 us, VALU ~1.0 us.
//    Variants that cut LDS traffic (KPT=2, amp-recompute) or removed the
//    barrier (wave-sync fence) all landed within/below measurement noise ->
//    this is the roofline; remaining dur_us is harness reset cost (~55 us).

__global__ __launch_bounds__(THREADS, 8)
void gmp_kernel(const float* __restrict__ x,
                const float* __restrict__ W,
                float* __restrict__ out) {
    __shared__ float4 zs[SS];    // (re0, im0, re1, im1) for this block's channel pair
    __shared__ float2 as2[SS];   // |z| for the two channels

    const int tid = threadIdx.x;
    const int b  = blockIdx.y;
    const int h  = blockIdx.z;               // channel pair: channels 2h, 2h+1
    const int n0 = blockIdx.x * THREADS;

    const float4* xg = (const float4*)x + (size_t)b * NN * 2;

    // Stage samples t = n0-10 .. n0+255 for this channel pair (zero-fill t<0).
    for (int s = tid; s < SS; s += THREADS) {
        const int t = n0 - HALO + s;
        float4 v = make_float4(0.f, 0.f, 0.f, 0.f);
        if (t >= 0) v = xg[2 * t + h];
        float2 a;
        a.x = sqrtf(fmaf(v.x, v.x, v.y * v.y));
        a.y = sqrtf(fmaf(v.z, v.z, v.w * v.w));
        zs[s] = v;
        as2[s] = a;
    }
    __syncthreads();

    // Weight rows for this pair — wave-uniform (h is SGPR) -> scalar loads.
    const float* W0 = W + (2 * h) * KK;
    const float* W1 = W + (2 * h + 1) * KK;

    float ar0 = 0.f, ai0 = 0.f, ar1 = 0.f, ai1 = 0.f;

    #pragma unroll
    for (int j = 0; j < MM; j++) {
        const int s = tid + j;
        const float4 v = zs[s];
        const float2 a = as2[s];
        // channel 2h
        {
            float p = W0[4 * MM + j];
            p = fmaf(p, a.x, W0[3 * MM + j]);
            p = fmaf(p, a.x, W0[2 * MM + j]);
            p = fmaf(p, a.x, W0[1 * MM + j]);
            p = fmaf(p, a.x, W0[0 * MM + j]);
            ar0 = fmaf(v.x, p, ar0);
            ai0 = fmaf(v.y, p, ai0);
        }
        // channel 2h+1
        {
            float p = W1[4 * MM + j];
            p = fmaf(p, a.y, W1[3 * MM + j]);
            p = fmaf(p, a.y, W1[2 * MM + j]);
            p = fmaf(p, a.y, W1[1 * MM + j]);
            p = fmaf(p, a.y, W1[0 * MM + j]);
            ar1 = fmaf(v.z, p, ar1);
            ai1 = fmaf(v.w, p, ai1);
        }
    }

    // out[b,n,c,{re,im}]: this thread writes channels 2h,2h+1 -> 16 contiguous bytes.
    const int n = n0 + tid;
    float4* og = (float4*)out + ((size_t)(b * NN + n) * 2 + h);
    *og = make_float4(ar0, ai0, ar1, ai1);
}

extern "C" void kernel_launch(void* const* d_in, const int* in_sizes, int n_in,
                              void* d_out, int out_size, void* d_ws, size_t ws_size,
                              hipStream_t stream) {
    const float* x = (const float*)d_in[0];   // [B,N,C,2] fp32
    const float* W = (const float*)d_in[1];   // [C,K] fp32
    float* out = (float*)d_out;               // [B,N,C,2] fp32

    dim3 grid(NN / THREADS, BB, 2);           // 128 x 8 x 2 = 2048 blocks
    gmp_kernel<<<grid, THREADS, 0, stream>>>(x, W, out);
}